// Round 3
// baseline (36.914 us; speedup 1.0000x reference)
//
#include <hip/hip_runtime.h>
#include <math.h>

__device__ __forceinline__ unsigned rotl32(unsigned v, int n) {
  return (v << n) | (v >> (32 - n));
}

// Reproduce jax.random.normal(jax.random.key(42), (n,), float32)[idx] under
// the (default) partitionable threefry scheme:
//   ctr = (hi, lo) = (idx >> 32, idx & 0xffffffff) = (0, idx) for idx < 2^32
//   (b0, b1) = threefry2x32_20rounds(key=(0,42), ctr)
//   bits = b0 ^ b1
//   u01  = bitcast((bits >> 9) | 0x3f800000) - 1.0
//   u    = max(lo, u01 * (hi - lo) + lo),  lo = nextafter(-1, 0); (hi-lo) == 2.0f
//   out  = sqrt(2) * erfinv(u)   (XLA Giles f32 polynomial)
__device__ float jax_threefry_normal42_part(unsigned idx) {
  const unsigned ks0 = 0u;
  const unsigned ks1 = 42u;
  const unsigned ks2 = 0x1BD11BDAu ^ 42u;
  unsigned x0 = 0u + ks0;    // hi word + key1
  unsigned x1 = idx + ks1;   // lo word + key2
  const unsigned ks[3] = {ks0, ks1, ks2};
  const int rA[4] = {13, 15, 26, 6};
  const int rB[4] = {17, 29, 16, 24};
#pragma unroll
  for (int i = 0; i < 5; ++i) {
    const int* r = (i & 1) ? rB : rA;
#pragma unroll
    for (int k = 0; k < 4; ++k) {
      x0 += x1;
      x1 = rotl32(x1, r[k]);
      x1 ^= x0;
    }
    x0 += ks[(i + 1) % 3];
    x1 += ks[(i + 2) % 3] + (unsigned)(i + 1);
  }
  unsigned bits = x0 ^ x1;
  float u01 = __uint_as_float((bits >> 9) | 0x3f800000u) - 1.0f;
  const float lo = -0.99999994f;
  float u = fmaxf(lo, fmaf(u01, 2.0f, lo));
  // XLA f32 erfinv polynomial (Giles)
  float w = -log1pf(-u * u);
  float p;
  if (w < 5.0f) {
    w = w - 2.5f;
    p = 2.81022636e-08f;
    p = fmaf(p, w, 3.43273939e-07f);
    p = fmaf(p, w, -3.5233877e-06f);
    p = fmaf(p, w, -4.39150654e-06f);
    p = fmaf(p, w, 0.00021858087f);
    p = fmaf(p, w, -0.00125372503f);
    p = fmaf(p, w, -0.00417768164f);
    p = fmaf(p, w, 0.246640727f);
    p = fmaf(p, w, 1.50140941f);
  } else {
    w = sqrtf(w) - 3.0f;
    p = -0.000200214257f;
    p = fmaf(p, w, 0.000100950558f);
    p = fmaf(p, w, 0.00134934322f);
    p = fmaf(p, w, -0.00367342844f);
    p = fmaf(p, w, 0.00573950773f);
    p = fmaf(p, w, -0.0076224613f);
    p = fmaf(p, w, 0.00943887047f);
    p = fmaf(p, w, 1.00167406f);
    p = fmaf(p, w, 2.83297682f);
  }
  return 1.41421354f * (p * u);
}

__device__ __forceinline__ float sigmoidf_(float v) {
  return 1.0f / (1.0f + expf(-v));
}

__global__ __launch_bounds__(256) void finance_moe_kernel(
    const float* __restrict__ emb,   // (ntok, 16)
    const float* __restrict__ vol,   // (ntok,)
    const float* __restrict__ risk,  // (ntok, 6)
    const float* __restrict__ rw,    // (6, 16)
    const float* __restrict__ rb,    // (6,)
    float* __restrict__ out,         // [ntok pred][ntok*6 probs][ntok assign]
    int ntok) {
  int t = blockIdx.x * blockDim.x + threadIdx.x;
  if (t >= ntok) return;

  // ---- load embeddings (64B contiguous per token) ----
  float x[16];
  {
    const float4* e4 = reinterpret_cast<const float4*>(emb) + (size_t)t * 4;
    float4 a0 = e4[0], a1 = e4[1], a2 = e4[2], a3 = e4[3];
    x[0] = a0.x; x[1] = a0.y; x[2] = a0.z; x[3] = a0.w;
    x[4] = a1.x; x[5] = a1.y; x[6] = a1.z; x[7] = a1.w;
    x[8] = a2.x; x[9] = a2.y; x[10] = a2.z; x[11] = a2.w;
    x[12] = a3.x; x[13] = a3.y; x[14] = a3.z; x[15] = a3.w;
  }

  // ---- router logits in float64 (argmax robust to accumulation order) ----
  double lg[6];
#pragma unroll
  for (int d = 0; d < 6; ++d) {
    double acc = 0.0;
#pragma unroll
    for (int h = 0; h < 16; ++h)
      acc = fma((double)x[h], (double)rw[d * 16 + h], acc);
    lg[d] = acc + (double)rb[d];
  }
  int amax = 0;
  {
    double best = lg[0];
#pragma unroll
    for (int d = 1; d < 6; ++d) {
      if (lg[d] > best) { best = lg[d]; amax = d; }
    }
  }
  float logits[6];
#pragma unroll
  for (int d = 0; d < 6; ++d) logits[d] = (float)lg[d];

  // ---- probs_base = softmax(logits) in f32 ----
  float m = logits[0];
#pragma unroll
  for (int d = 1; d < 6; ++d) m = fmaxf(m, logits[d]);
  float eb[6], se = 0.0f;
#pragma unroll
  for (int d = 0; d < 6; ++d) { eb[d] = expf(logits[d] - m); se += eb[d]; }
  float pb[6];
#pragma unroll
  for (int d = 0; d < 6; ++d) pb[d] = eb[d] / se;

  // ---- adjusted probs (training straight-through branch) ----
  const float MKT[6] = {0.5f, -1.0f, 0.8f, 0.6f, 1.5f, 0.4f};
  const float RSK[6] = {0.5f, -0.8f, 0.6f, 1.0f, 1.2f, 0.5f};
  float v = vol[t];
  float rk[6];
  {
    const float2* r2 = reinterpret_cast<const float2*>(risk) + (size_t)t * 3;
    float2 q0 = r2[0], q1 = r2[1], q2 = r2[2];
    rk[0] = q0.x; rk[1] = q0.y; rk[2] = q1.x;
    rk[3] = q1.y; rk[4] = q2.x; rk[5] = q2.y;
  }
  float sd[6];
#pragma unroll
  for (int d = 0; d < 6; ++d) {
    float adj = logits[d] + (v * MKT[d]) * 0.3f + (rk[d] * RSK[d]) * 0.3f;
    sd[d] = adj / 1.2f;
  }
  float m2 = sd[0];
#pragma unroll
  for (int d = 1; d < 6; ++d) m2 = fmaxf(m2, sd[d]);
  float ed[6], se2 = 0.0f;
#pragma unroll
  for (int d = 0; d < 6; ++d) { ed[d] = expf(sd[d] - m2); se2 += ed[d]; }
  float rp[6];
#pragma unroll
  for (int d = 0; d < 6; ++d) {
    float pd = ed[d] / se2;
    rp[d] = (pb[d] + pd) - pd;  // literal straight-through forward value
  }

  // ---- expert prediction for assigned expert ----
  float sum = 0.0f;
#pragma unroll
  for (int h = 0; h < 16; ++h) sum += x[h];
  float mean = sum * (1.0f / 16.0f);
  float ss = 0.0f;
#pragma unroll
  for (int h = 0; h < 16; ++h) {
    float dv = x[h] - mean;
    ss += dv * dv;
  }
  float stdv = sqrtf(ss * (1.0f / 15.0f));  // ddof=1

  float pred;
  if (amax == 0) {
    float s4 = ((x[0] + x[1]) + x[2]) + x[3];
    pred = tanhf(s4 * 0.25f) * (1.0f + stdv);
  } else if (amax == 1) {
    pred = sigmoidf_(mean) * 0.3f - 0.15f;
  } else if (amax == 2) {
    float s6 = ((((x[0] + x[1]) + x[2]) + x[3]) + x[4]) + x[5];
    float s610 = ((x[6] + x[7]) + x[8]) + x[9];
    pred = (s6 * (1.0f / 6.0f)) * 0.8f + sinf((s610 * 0.25f) * 3.14159f) * 0.4f;
  } else if (amax == 3) {
    float s8 = ((((((x[0] + x[1]) + x[2]) + x[3]) + x[4]) + x[5]) + x[6]) + x[7];
    float noise = jax_threefry_normal42_part((unsigned)t) * 0.05f;
    pred = tanhf(s8 * 0.125f) * 0.9f + noise;
  } else if (amax == 4) {
    pred = powf(fmaxf(mean, 0.0f), 1.2f) + stdv * 2.5f - 0.5f;
  } else {
    pred = sigmoidf_(mean) * 0.4f + tanhf(stdv) * 0.2f;
  }

  // ---- stores ----
  out[t] = pred;
  float2* po = reinterpret_cast<float2*>(out + ntok) + (size_t)t * 3;
  po[0] = make_float2(rp[0], rp[1]);
  po[1] = make_float2(rp[2], rp[3]);
  po[2] = make_float2(rp[4], rp[5]);
  out[(size_t)ntok * 7 + t] = (float)amax;
}

extern "C" void kernel_launch(void* const* d_in, const int* in_sizes, int n_in,
                              void* d_out, int out_size, void* d_ws, size_t ws_size,
                              hipStream_t stream) {
  const float* emb = (const float*)d_in[0];
  const float* vol = (const float*)d_in[1];
  const float* risk = (const float*)d_in[2];
  const float* rw = (const float*)d_in[3];
  const float* rb = (const float*)d_in[4];
  float* out = (float*)d_out;
  int ntok = in_sizes[0] / 16;  // B*S
  int block = 256;
  int grid = (ntok + block - 1) / block;
  hipLaunchKernelGGL(finance_moe_kernel, dim3(grid), dim3(block), 0, stream,
                     emb, vol, risk, rw, rb, out, ntok);
}

// Round 4
// 25.578 us; speedup vs baseline: 1.4432x; 1.4432x over previous
//
#include <hip/hip_runtime.h>
#include <math.h>

__device__ __forceinline__ unsigned rotl32(unsigned v, int n) {
  return (v << n) | (v >> (32 - n));
}

__device__ __forceinline__ float frcp(float x) { return __builtin_amdgcn_rcpf(x); }

__device__ __forceinline__ float ftanh(float x) {
  // tanh(x) = 1 - 2/(e^{2x}+1); exact limits at +-inf via v_exp/v_rcp
  float t = __expf(2.0f * x);
  return 1.0f - 2.0f * frcp(t + 1.0f);
}

__device__ __forceinline__ float fsigmoid(float x) {
  return frcp(1.0f + __expf(-x));
}

// jax.random.normal(key(42), (n,), f32)[idx], partitionable threefry scheme:
// ctr=(0, idx), (b0,b1)=threefry2x32_20(key=(0,42), ctr), bits=b0^b1,
// u in [nextafter(-1,0), 1), out = sqrt(2)*erfinv(u) (Giles f32 poly).
__device__ float jax_threefry_normal42_part(unsigned idx) {
  const unsigned ks0 = 0u;
  const unsigned ks1 = 42u;
  const unsigned ks2 = 0x1BD11BDAu ^ 42u;
  unsigned x0 = 0u + ks0;
  unsigned x1 = idx + ks1;
  const unsigned ks[3] = {ks0, ks1, ks2};
  const int rA[4] = {13, 15, 26, 6};
  const int rB[4] = {17, 29, 16, 24};
#pragma unroll
  for (int i = 0; i < 5; ++i) {
    const int* r = (i & 1) ? rB : rA;
#pragma unroll
    for (int k = 0; k < 4; ++k) {
      x0 += x1;
      x1 = rotl32(x1, r[k]);
      x1 ^= x0;
    }
    x0 += ks[(i + 1) % 3];
    x1 += ks[(i + 2) % 3] + (unsigned)(i + 1);
  }
  unsigned bits = x0 ^ x1;
  float u01 = __uint_as_float((bits >> 9) | 0x3f800000u) - 1.0f;
  const float lo = -0.99999994f;
  float u = fmaxf(lo, fmaf(u01, 2.0f, lo));
  float w = -__logf(1.0f - u * u);
  float p;
  if (w < 5.0f) {
    w = w - 2.5f;
    p = 2.81022636e-08f;
    p = fmaf(p, w, 3.43273939e-07f);
    p = fmaf(p, w, -3.5233877e-06f);
    p = fmaf(p, w, -4.39150654e-06f);
    p = fmaf(p, w, 0.00021858087f);
    p = fmaf(p, w, -0.00125372503f);
    p = fmaf(p, w, -0.00417768164f);
    p = fmaf(p, w, 0.246640727f);
    p = fmaf(p, w, 1.50140941f);
  } else {
    w = sqrtf(w) - 3.0f;
    p = -0.000200214257f;
    p = fmaf(p, w, 0.000100950558f);
    p = fmaf(p, w, 0.00134934322f);
    p = fmaf(p, w, -0.00367342844f);
    p = fmaf(p, w, 0.00573950773f);
    p = fmaf(p, w, -0.0076224613f);
    p = fmaf(p, w, 0.00943887047f);
    p = fmaf(p, w, 1.00167406f);
    p = fmaf(p, w, 2.83297682f);
  }
  return 1.41421354f * (p * u);
}

__global__ __launch_bounds__(256) void finance_moe_kernel(
    const float* __restrict__ emb,   // (ntok, 16)
    const float* __restrict__ vol,   // (ntok,)
    const float* __restrict__ risk,  // (ntok, 6)
    const float* __restrict__ rw,    // (6, 16)
    const float* __restrict__ rb,    // (6,)
    float* __restrict__ out,         // [ntok pred][ntok*6 probs][ntok assign]
    int ntok) {
  int t = blockIdx.x * blockDim.x + threadIdx.x;
  if (t >= ntok) return;

  // ---- load embeddings (64B contiguous per token) ----
  float x[16];
  {
    const float4* e4 = reinterpret_cast<const float4*>(emb) + (size_t)t * 4;
    float4 a0 = e4[0], a1 = e4[1], a2 = e4[2], a3 = e4[3];
    x[0] = a0.x; x[1] = a0.y; x[2] = a0.z; x[3] = a0.w;
    x[4] = a1.x; x[5] = a1.y; x[6] = a1.z; x[7] = a1.w;
    x[8] = a2.x; x[9] = a2.y; x[10] = a2.z; x[11] = a2.w;
    x[12] = a3.x; x[13] = a3.y; x[14] = a3.z; x[15] = a3.w;
  }

  // ---- router logits in float64 (argmax must match f64 np reference) ----
  double lg[6];
#pragma unroll
  for (int d = 0; d < 6; ++d) {
    double acc = 0.0;
#pragma unroll
    for (int h = 0; h < 16; ++h)
      acc = fma((double)x[h], (double)rw[d * 16 + h], acc);
    lg[d] = acc + (double)rb[d];
  }
  int amax = 0;
  {
    double best = lg[0];
#pragma unroll
    for (int d = 1; d < 6; ++d) {
      if (lg[d] > best) { best = lg[d]; amax = d; }
    }
  }
  float logits[6];
#pragma unroll
  for (int d = 0; d < 6; ++d) logits[d] = (float)lg[d];

  // ---- probs_base = softmax(logits) ----
  float m = logits[0];
#pragma unroll
  for (int d = 1; d < 6; ++d) m = fmaxf(m, logits[d]);
  float eb[6], se = 0.0f;
#pragma unroll
  for (int d = 0; d < 6; ++d) { eb[d] = __expf(logits[d] - m); se += eb[d]; }
  float inv_se = frcp(se);
  float pb[6];
#pragma unroll
  for (int d = 0; d < 6; ++d) pb[d] = eb[d] * inv_se;

  // ---- adjusted probs (training straight-through branch) ----
  const float MKT[6] = {0.5f, -1.0f, 0.8f, 0.6f, 1.5f, 0.4f};
  const float RSK[6] = {0.5f, -0.8f, 0.6f, 1.0f, 1.2f, 0.5f};
  float v = vol[t];
  float rk[6];
  {
    const float2* r2 = reinterpret_cast<const float2*>(risk) + (size_t)t * 3;
    float2 q0 = r2[0], q1 = r2[1], q2 = r2[2];
    rk[0] = q0.x; rk[1] = q0.y; rk[2] = q1.x;
    rk[3] = q1.y; rk[4] = q2.x; rk[5] = q2.y;
  }
  const float INV12 = 0.83333333333333333f;  // 1/1.2
  float sd[6];
#pragma unroll
  for (int d = 0; d < 6; ++d) {
    float adj = logits[d] + (v * MKT[d]) * 0.3f + (rk[d] * RSK[d]) * 0.3f;
    sd[d] = adj * INV12;
  }
  float m2 = sd[0];
#pragma unroll
  for (int d = 1; d < 6; ++d) m2 = fmaxf(m2, sd[d]);
  float ed[6], se2 = 0.0f;
#pragma unroll
  for (int d = 0; d < 6; ++d) { ed[d] = __expf(sd[d] - m2); se2 += ed[d]; }
  float inv_se2 = frcp(se2);
  float rp[6];
#pragma unroll
  for (int d = 0; d < 6; ++d) {
    float pd = ed[d] * inv_se2;
    rp[d] = (pb[d] + pd) - pd;  // literal straight-through forward value
  }

  // ---- expert prediction for assigned expert ----
  float sum = 0.0f;
#pragma unroll
  for (int h = 0; h < 16; ++h) sum += x[h];
  float mean = sum * (1.0f / 16.0f);
  float ss = 0.0f;
#pragma unroll
  for (int h = 0; h < 16; ++h) {
    float dv = x[h] - mean;
    ss += dv * dv;
  }
  float stdv = sqrtf(ss * (1.0f / 15.0f));  // ddof=1

  float pred;
  if (amax == 0) {
    float s4 = ((x[0] + x[1]) + x[2]) + x[3];
    pred = ftanh(s4 * 0.25f) * (1.0f + stdv);
  } else if (amax == 1) {
    pred = fsigmoid(mean) * 0.3f - 0.15f;
  } else if (amax == 2) {
    float s6 = ((((x[0] + x[1]) + x[2]) + x[3]) + x[4]) + x[5];
    float s610 = ((x[6] + x[7]) + x[8]) + x[9];
    pred = (s6 * (1.0f / 6.0f)) * 0.8f + __sinf((s610 * 0.25f) * 3.14159f) * 0.4f;
  } else if (amax == 3) {
    float s8 = ((((((x[0] + x[1]) + x[2]) + x[3]) + x[4]) + x[5]) + x[6]) + x[7];
    float noise = jax_threefry_normal42_part((unsigned)t) * 0.05f;
    pred = ftanh(s8 * 0.125f) * 0.9f + noise;
  } else if (amax == 4) {
    // mean>=0 after relu; 0^1.2 -> exp(-inf) = 0 naturally
    float r = fmaxf(mean, 0.0f);
    pred = __expf(1.2f * __logf(r)) + stdv * 2.5f - 0.5f;
  } else {
    pred = fsigmoid(mean) * 0.4f + ftanh(stdv) * 0.2f;
  }

  // ---- stores ----
  out[t] = pred;
  float2* po = reinterpret_cast<float2*>(out + ntok) + (size_t)t * 3;
  po[0] = make_float2(rp[0], rp[1]);
  po[1] = make_float2(rp[2], rp[3]);
  po[2] = make_float2(rp[4], rp[5]);
  out[(size_t)ntok * 7 + t] = (float)amax;
}

extern "C" void kernel_launch(void* const* d_in, const int* in_sizes, int n_in,
                              void* d_out, int out_size, void* d_ws, size_t ws_size,
                              hipStream_t stream) {
  const float* emb = (const float*)d_in[0];
  const float* vol = (const float*)d_in[1];
  const float* risk = (const float*)d_in[2];
  const float* rw = (const float*)d_in[3];
  const float* rb = (const float*)d_in[4];
  float* out = (float*)d_out;
  int ntok = in_sizes[0] / 16;  // B*S
  int block = 256;
  int grid = (ntok + block - 1) / block;
  hipLaunchKernelGGL(finance_moe_kernel, dim3(grid), dim3(block), 0, stream,
                     emb, vol, risk, rw, rb, out, ntok);
}

// Round 5
// 22.358 us; speedup vs baseline: 1.6511x; 1.1440x over previous
//
#include <hip/hip_runtime.h>
#include <math.h>

__device__ __forceinline__ unsigned rotl32(unsigned v, int n) {
  return (v << n) | (v >> (32 - n));
}

__device__ __forceinline__ float frcp(float x) { return __builtin_amdgcn_rcpf(x); }

__device__ __forceinline__ float ftanh(float x) {
  // tanh(x) = 1 - 2/(e^{2x}+1)
  float t = __expf(2.0f * x);
  return 1.0f - 2.0f * frcp(t + 1.0f);
}

__device__ __forceinline__ float fsigmoid(float x) {
  return frcp(1.0f + __expf(-x));
}

// jax.random.normal(key(42), (n,), f32)[idx], partitionable threefry scheme.
__device__ float jax_threefry_normal42_part(unsigned idx) {
  const unsigned ks0 = 0u;
  const unsigned ks1 = 42u;
  const unsigned ks2 = 0x1BD11BDAu ^ 42u;
  unsigned x0 = 0u + ks0;
  unsigned x1 = idx + ks1;
  const unsigned ks[3] = {ks0, ks1, ks2};
  const int rA[4] = {13, 15, 26, 6};
  const int rB[4] = {17, 29, 16, 24};
#pragma unroll
  for (int i = 0; i < 5; ++i) {
    const int* r = (i & 1) ? rB : rA;
#pragma unroll
    for (int k = 0; k < 4; ++k) {
      x0 += x1;
      x1 = rotl32(x1, r[k]);
      x1 ^= x0;
    }
    x0 += ks[(i + 1) % 3];
    x1 += ks[(i + 2) % 3] + (unsigned)(i + 1);
  }
  unsigned bits = x0 ^ x1;
  float u01 = __uint_as_float((bits >> 9) | 0x3f800000u) - 1.0f;
  const float lo = -0.99999994f;
  float u = fmaxf(lo, fmaf(u01, 2.0f, lo));
  float w = -__logf(1.0f - u * u);
  float p;
  if (w < 5.0f) {
    w = w - 2.5f;
    p = 2.81022636e-08f;
    p = fmaf(p, w, 3.43273939e-07f);
    p = fmaf(p, w, -3.5233877e-06f);
    p = fmaf(p, w, -4.39150654e-06f);
    p = fmaf(p, w, 0.00021858087f);
    p = fmaf(p, w, -0.00125372503f);
    p = fmaf(p, w, -0.00417768164f);
    p = fmaf(p, w, 0.246640727f);
    p = fmaf(p, w, 1.50140941f);
  } else {
    w = sqrtf(w) - 3.0f;
    p = -0.000200214257f;
    p = fmaf(p, w, 0.000100950558f);
    p = fmaf(p, w, 0.00134934322f);
    p = fmaf(p, w, -0.00367342844f);
    p = fmaf(p, w, 0.00573950773f);
    p = fmaf(p, w, -0.0076224613f);
    p = fmaf(p, w, 0.00943887047f);
    p = fmaf(p, w, 1.00167406f);
    p = fmaf(p, w, 2.83297682f);
  }
  return 1.41421354f * (p * u);
}

__global__ __launch_bounds__(256) void finance_moe_kernel(
    const float* __restrict__ emb,  // (ntok, 16)
    const float* __restrict__ rw,   // (6, 16)
    const float* __restrict__ rb,   // (6,)
    float* __restrict__ out,        // [ntok pred][ntok*6 probs][ntok assign]
    int ntok) {
  int t = blockIdx.x * blockDim.x + threadIdx.x;
  if (t >= ntok) return;

  // ---- load embeddings (64B contiguous per token) ----
  float x[16];
  {
    const float4* e4 = reinterpret_cast<const float4*>(emb) + (size_t)t * 4;
    float4 a0 = e4[0], a1 = e4[1], a2 = e4[2], a3 = e4[3];
    x[0] = a0.x; x[1] = a0.y; x[2] = a0.z; x[3] = a0.w;
    x[4] = a1.x; x[5] = a1.y; x[6] = a1.z; x[7] = a1.w;
    x[8] = a2.x; x[9] = a2.y; x[10] = a2.z; x[11] = a2.w;
    x[12] = a3.x; x[13] = a3.y; x[14] = a3.z; x[15] = a3.w;
  }

  // ---- router logits in f32 ----
  float lg[6];
#pragma unroll
  for (int d = 0; d < 6; ++d) {
    float acc = 0.0f;
#pragma unroll
    for (int h = 0; h < 16; ++h) acc = fmaf(x[h], rw[d * 16 + h], acc);
    lg[d] = acc + rb[d];
  }

  // ---- argmax: f32 with top-2 gap test; f64 fallback for near-ties ----
  int a1 = 0, a2 = 0;
  float b1 = lg[0], b2 = -1e30f;
#pragma unroll
  for (int d = 1; d < 6; ++d) {
    if (lg[d] > b1) { b2 = b1; a2 = a1; b1 = lg[d]; a1 = d; }
    else if (lg[d] > b2) { b2 = lg[d]; a2 = d; }
  }
  int amax = a1;
  if (b1 - b2 < 2e-5f) {  // f32 chain error <= ~1e-6; 20x margin
    double A = 0.0, B = 0.0;
#pragma unroll
    for (int h = 0; h < 16; ++h) {
      A = fma((double)x[h], (double)rw[a1 * 16 + h], A);
      B = fma((double)x[h], (double)rw[a2 * 16 + h], B);
    }
    A += (double)rb[a1];
    B += (double)rb[a2];
    // np.argmax first-max semantics on tie
    amax = (B > A || (B == A && a2 < a1)) ? a2 : a1;
  }

  // ---- probs_base = softmax(logits); routing_probs forward == probs_base ----
  float m = lg[0];
#pragma unroll
  for (int d = 1; d < 6; ++d) m = fmaxf(m, lg[d]);
  float eb[6], se = 0.0f;
#pragma unroll
  for (int d = 0; d < 6; ++d) { eb[d] = __expf(lg[d] - m); se += eb[d]; }
  float inv_se = frcp(se);
  float pb[6];
#pragma unroll
  for (int d = 0; d < 6; ++d) pb[d] = eb[d] * inv_se;

  // ---- expert predictions (straight-line, select at end) ----
  float sum = 0.0f;
#pragma unroll
  for (int h = 0; h < 16; ++h) sum += x[h];
  float mean = sum * (1.0f / 16.0f);
  float ss = 0.0f;
#pragma unroll
  for (int h = 0; h < 16; ++h) {
    float dv = x[h] - mean;
    ss += dv * dv;
  }
  float stdv = sqrtf(ss * (1.0f / 15.0f));  // ddof=1

  float s4 = ((x[0] + x[1]) + x[2]) + x[3];
  float s6 = ((((x[0] + x[1]) + x[2]) + x[3]) + x[4]) + x[5];
  float s610 = ((x[6] + x[7]) + x[8]) + x[9];
  float s8 = s6 + x[6] + x[7];

  float sig = fsigmoid(mean);
  float p0 = ftanh(s4 * 0.25f) * (1.0f + stdv);
  float p1 = sig * 0.3f - 0.15f;
  float p2 = (s6 * (1.0f / 6.0f)) * 0.8f + __sinf((s610 * 0.25f) * 3.14159f) * 0.4f;
  float noise = jax_threefry_normal42_part((unsigned)t) * 0.05f;
  float p3 = ftanh(s8 * 0.125f) * 0.9f + noise;
  float r4 = fmaxf(mean, 0.0f);
  float p4 = __expf(1.2f * __logf(r4)) + stdv * 2.5f - 0.5f;
  float p5 = sig * 0.4f + ftanh(stdv) * 0.2f;

  float pred = (amax == 0) ? p0
             : (amax == 1) ? p1
             : (amax == 2) ? p2
             : (amax == 3) ? p3
             : (amax == 4) ? p4
                           : p5;

  // ---- stores ----
  out[t] = pred;
  float2* po = reinterpret_cast<float2*>(out + ntok) + (size_t)t * 3;
  po[0] = make_float2(pb[0], pb[1]);
  po[1] = make_float2(pb[2], pb[3]);
  po[2] = make_float2(pb[4], pb[5]);
  out[(size_t)ntok * 7 + t] = (float)amax;
}

extern "C" void kernel_launch(void* const* d_in, const int* in_sizes, int n_in,
                              void* d_out, int out_size, void* d_ws, size_t ws_size,
                              hipStream_t stream) {
  const float* emb = (const float*)d_in[0];
  const float* rw = (const float*)d_in[3];
  const float* rb = (const float*)d_in[4];
  float* out = (float*)d_out;
  int ntok = in_sizes[0] / 16;  // B*S
  int block = 256;
  int grid = (ntok + block - 1) / block;
  hipLaunchKernelGGL(finance_moe_kernel, dim3(grid), dim3(block), 0, stream,
                     emb, rw, rb, out, ntok);
}